// Round 5
// baseline (199.907 us; speedup 1.0000x reference)
//
#include <hip/hip_runtime.h>
#include <hip/hip_bf16.h>

#define DD 256
#define CC 104
#define NSL 8      // feature slices: 8 x 32 dims (64B) — one slice per XCD

typedef __bf16 bf16x8 __attribute__((ext_vector_type(8)));
typedef float  f32x4  __attribute__((ext_vector_type(4)));

__device__ inline float bu2f(unsigned short u) {
    return __uint_as_float(((unsigned)u) << 16);
}
__device__ inline unsigned short f2bu(float f) {
    __hip_bfloat16 h = __float2bfloat16(f);
    return *reinterpret_cast<unsigned short*>(&h);
}

// ---------------------------------------------------------------------------
// Kernel 1: prep — per-edge boundaries/tokens/last-token + W,Wc -> bf16 frags.
// Fragment layout (g = group, s = lane, j<8):
//   frag[g*512 + s*8 + j] = Wsrc[(nt*16 + (s&15))*256 + k0*32 + (s>>4)*8 + j]
//   W: g = k0*16 + nt (8 x 16);  Wc: g = k0*8 + nt (8 x 8, rows padded to 128)
// ---------------------------------------------------------------------------
__global__ void prep_all(
    const int* __restrict__ token_id,
    const int* __restrict__ src_idx,
    const int* __restrict__ dst_idx,
    int* __restrict__ seg_start,
    int* __restrict__ seg_end,
    int* __restrict__ edge_tok,
    int* __restrict__ last_tok,
    int E, int PB,
    const float* __restrict__ W,
    const float* __restrict__ Wc,
    __hip_bfloat16* __restrict__ Wfrag,
    __hip_bfloat16* __restrict__ Wcfrag)
{
    const int b = blockIdx.x;
    const int t = threadIdx.x;
    if (b < PB) {
        int e = b * 256 + t;
        if (e >= E) return;
        int d = dst_idx[e];
        int tok = token_id[src_idx[e]];
        edge_tok[e] = tok;
        if (e == 0 || dst_idx[e - 1] != d) seg_start[d] = e;
        if (e == E - 1 || dst_idx[e + 1] != d) { seg_end[d] = e + 1; last_tok[d] = tok; }
        return;
    }
    if (b < PB + 32) {                      // W fragment reorder
        int idx  = (b - PB) * 256 + t;      // 0..8191
        int lane = idx & 63, g = idx >> 6;  // g = k0*16 + nt
        int nt = g & 15, k0 = g >> 4;
        int r = nt * 16 + (lane & 15);
        int c = k0 * 32 + (lane >> 4) * 8;
        const float* src = W + (size_t)r * DD + c;
        float4 v0 = *(const float4*)(src);
        float4 v1 = *(const float4*)(src + 4);
        uint4 pk;
        pk.x = (unsigned)f2bu(v0.x) | ((unsigned)f2bu(v0.y) << 16);
        pk.y = (unsigned)f2bu(v0.z) | ((unsigned)f2bu(v0.w) << 16);
        pk.z = (unsigned)f2bu(v1.x) | ((unsigned)f2bu(v1.y) << 16);
        pk.w = (unsigned)f2bu(v1.z) | ((unsigned)f2bu(v1.w) << 16);
        *(uint4*)(Wfrag + (size_t)idx * 8) = pk;
        return;
    }
    {                                       // Wc fragment reorder (padded)
        int idx  = (b - PB - 32) * 256 + t; // 0..4095
        int lane = idx & 63, g = idx >> 6;  // g = k0*8 + nt
        int nt = g & 7, k0 = g >> 3;
        int r = nt * 16 + (lane & 15);      // 0..127
        int c = k0 * 32 + (lane >> 4) * 8;
        float4 v0 = make_float4(0.f,0.f,0.f,0.f);
        float4 v1 = make_float4(0.f,0.f,0.f,0.f);
        if (r < CC) {
            const float* src = Wc + (size_t)r * DD + c;
            v0 = *(const float4*)(src);
            v1 = *(const float4*)(src + 4);
        }
        uint4 pk;
        pk.x = (unsigned)f2bu(v0.x) | ((unsigned)f2bu(v0.y) << 16);
        pk.y = (unsigned)f2bu(v0.z) | ((unsigned)f2bu(v0.w) << 16);
        pk.z = (unsigned)f2bu(v1.x) | ((unsigned)f2bu(v1.y) << 16);
        pk.w = (unsigned)f2bu(v1.z) | ((unsigned)f2bu(v1.w) << 16);
        *(uint4*)(Wcfrag + (size_t)idx * 8) = pk;
    }
}

// ---------------------------------------------------------------------------
// Kernel 2: We = emb @ W^T for ALL tokens (dense streaming MFMA GEMM).
// R12: Webuf and embb are written SLICE-MAJOR: [slice=dim/32][V][32 dims].
// Slice-major makes each 3.2MB slice a contiguous region so one XCD's L2
// can keep exactly its slice resident during the gather kernel.
// ---------------------------------------------------------------------------
__global__ __launch_bounds__(256, 3) void we_gemm(
    const float* __restrict__ emb,             // [V,256] fp32
    const __hip_bfloat16* __restrict__ Wfrag,  // 128 groups x 512
    __hip_bfloat16* __restrict__ Webuf,        // [8][V][32] bf16 out
    __hip_bfloat16* __restrict__ embb,         // [8][V][32] bf16 out
    int V)
{
    __shared__ __hip_bfloat16 lds[32 * 512];   // 32KB
    const int t    = threadIdx.x;
    const int lane = t & 63;
    const int w    = t >> 6;
    const int quad = lane >> 4;
    const int l16  = lane & 15;
    const int mrow = blockIdx.x * 64 + w * 16 + l16;
    const int row  = min(mrow, V - 1);

    // stream emb row fp32 -> bf16 frags (+ embb slice-major side-write)
    bf16x8 bfrag[8];
#pragma unroll
    for (int k0 = 0; k0 < 8; ++k0) {
        const float* src = emb + (size_t)row * DD + k0 * 32 + quad * 8;
        float4 v0 = *(const float4*)(src);
        float4 v1 = *(const float4*)(src + 4);
        uint4 pk;
        pk.x = (unsigned)f2bu(v0.x) | ((unsigned)f2bu(v0.y) << 16);
        pk.y = (unsigned)f2bu(v0.z) | ((unsigned)f2bu(v0.w) << 16);
        pk.z = (unsigned)f2bu(v1.x) | ((unsigned)f2bu(v1.y) << 16);
        pk.w = (unsigned)f2bu(v1.z) | ((unsigned)f2bu(v1.w) << 16);
        bfrag[k0] = *(bf16x8*)&pk;
        if (mrow < V)   // slice k0, chunk quad*8 within slice
            *(uint4*)(embb + (size_t)k0 * V * 32 + (size_t)row * 32 + quad * 8) = pk;
    }

    f32x4 acc[16];
#pragma unroll
    for (int nt = 0; nt < 16; ++nt) acc[nt] = (f32x4){0.f,0.f,0.f,0.f};

    for (int p = 0; p < 4; ++p) {
        if (p) __syncthreads();
        // straight-copy groups [32p, 32p+32): 32KB
#pragma unroll
        for (int it = 0; it < 8; ++it) {
            int idx = it * 256 + t;
            *(uint4*)(lds + (size_t)idx * 8) =
                *(const uint4*)(Wfrag + (size_t)p * 16384 + (size_t)idx * 8);
        }
        __syncthreads();
#pragma unroll
        for (int kl = 0; kl < 2; ++kl) {
            int k0 = p * 2 + kl;
#pragma unroll
            for (int nt = 0; nt < 16; ++nt) {
                bf16x8 wf = *(const bf16x8*)(lds + (kl * 16 + nt) * 512 + lane * 8);
                acc[nt] = __builtin_amdgcn_mfma_f32_16x16x32_bf16(wf, bfrag[k0], acc[nt], 0, 0, 0);
            }
        }
    }

    if (mrow < V) {
#pragma unroll
        for (int nt = 0; nt < 16; ++nt) {
            int c0 = nt * 16 + quad * 4;    // starting dim of this 4-dim piece
            ushort4 o;
            o.x = f2bu(acc[nt][0]);
            o.y = f2bu(acc[nt][1]);
            o.z = f2bu(acc[nt][2]);
            o.w = f2bu(acc[nt][3]);
            *(ushort4*)(Webuf + (size_t)(c0 >> 5) * V * 32 +
                        (size_t)mrow * 32 + (c0 & 31)) = o;
        }
    }
}

// ---------------------------------------------------------------------------
// Kernel 3: segment sum + rnn epilogue, XCD-SLICED (R12).
// R8-R11 lesson: schedule changes (4-deep pipeline / 16-wide clusters /
// shfl+sched_barrier) all landed at 52-56us with hbm ~3.5TB/s -> the limit
// is the L2-miss path: every XCD pulled the whole 25.6MB Webuf through its
// 4MB L2 (FETCH 156MB = 6x table size, continuous thrash).
// Fix: slice D=256 into 8 x 32-dim slices; slice = blockIdx&7 so (with
// round-robin dispatch) XCD k only touches slice k: 3.2MB We + 3.2MB embb
// slices stay ~L2-resident; each table byte fetched ~once chip-wide.
// Wave shape: 16 dsts x 4 lanes (16B each). Each 4-lane group accumulates
// its dst's children IN-LANE (no cross-lane reduce; epilogue is elementwise
// in d so slices are independent). 2-way unrolled gather loop.
// ---------------------------------------------------------------------------
__global__ __launch_bounds__(256, 8) void seg_rnn_kernel(
    const __hip_bfloat16* __restrict__ Webuf,   // [8][V][32]
    const __hip_bfloat16* __restrict__ embb,    // [8][V][32]
    const int* __restrict__ edge_tok,
    const int* __restrict__ seg_start,
    const int* __restrict__ seg_end,
    const int* __restrict__ last_tok,
    const float* __restrict__ bvec,
    __hip_bfloat16* __restrict__ ftb,           // [8][n_dst][32]
    int n_dst, int V)
{
    const int bid  = blockIdx.x;
    const int sl   = bid & 7;                   // slice == XCD (round-robin)
    const int g    = bid >> 3;                  // dst-group of 64
    const int t    = threadIdx.x;
    const int wv   = t >> 6;
    const int lane = t & 63;
    const int grp  = lane >> 2;                 // dst within wave [0,16)
    const int c    = lane & 3;                  // 16B chunk within 64B slice

    int d = g * 64 + wv * 16 + grp;
    bool dok = d < n_dst;
    int dc = dok ? d : n_dst - 1;
    int s  = seg_start[dc];
    int e  = seg_end[dc];
    int lt = last_tok[dc];
    int n  = dok ? (e - 1 - s) : 0;             // children to sum (deg-1)

    const __hip_bfloat16* wsl = Webuf + (size_t)sl * V * 32;
    const __hip_bfloat16* esl = embb  + (size_t)sl * V * 32;
    // last-message slice read (1 line per 4-lane group, overlaps the loop)
    uint4 lm = *(const uint4*)(esl + (size_t)lt * 32 + c * 8);

    float acc[8] = {0.f,0.f,0.f,0.f,0.f,0.f,0.f,0.f};

    for (int j = 0; ; j += 2) {
        bool a0 = j < n, a1 = j + 1 < n;
        if (!__any(a0)) break;
        uint4 u0 = make_uint4(0u,0u,0u,0u);
        uint4 u1 = make_uint4(0u,0u,0u,0u);
        if (a0) {
            int t0 = edge_tok[s + j];
            u0 = *(const uint4*)(wsl + (size_t)t0 * 32 + c * 8);
        }
        if (a1) {
            int t1 = edge_tok[s + j + 1];
            u1 = *(const uint4*)(wsl + (size_t)t1 * 32 + c * 8);
        }
        const unsigned* p0 = (const unsigned*)&u0;
        const unsigned* p1 = (const unsigned*)&u1;
#pragma unroll
        for (int k = 0; k < 4; ++k) {   // masked-off lanes loaded 0 -> adds 0
            acc[2*k]   += __uint_as_float(p0[k] << 16)
                        + __uint_as_float(p1[k] << 16);
            acc[2*k+1] += __uint_as_float(p0[k] & 0xffff0000u)
                        + __uint_as_float(p1[k] & 0xffff0000u);
        }
    }

    bool gate = n > 0;
    // epilogue: each lane owns 8 dims of its dst — no cross-lane reduce
    float4 b0 = *(const float4*)(bvec + sl * 32 + c * 8);
    float4 b1 = *(const float4*)(bvec + sl * 32 + c * 8 + 4);
    float bl[8] = {b0.x, b0.y, b0.z, b0.w, b1.x, b1.y, b1.z, b1.w};
    const unsigned* lmd = (const unsigned*)&lm;
    uint4 o;
    unsigned* od = (unsigned*)&o;
#pragma unroll
    for (int k = 0; k < 4; ++k) {
        float lo = __uint_as_float(lmd[k] << 16);
        float hi = __uint_as_float(lmd[k] & 0xffff0000u);
        float v0 = lo + (gate ? fmaxf(acc[2*k]   + bl[2*k],   0.f) : 0.f);
        float v1 = hi + (gate ? fmaxf(acc[2*k+1] + bl[2*k+1], 0.f) : 0.f);
        od[k] = (unsigned)f2bu(v0) | ((unsigned)f2bu(v1) << 16);
    }
    if (dok)    // wave stores 16 dsts x 64B = 1KB contiguous per slice
        *(uint4*)(ftb + (size_t)sl * n_dst * 32 + (size_t)d * 32 + c * 8) = o;
}

// ---------------------------------------------------------------------------
// Kernel 4: classifier GEMM. 64-row blocks, Wcfrag staged via straight
// 32KB copies (2 phases). R12: ftb is slice-major [8][M][32]; k0 == slice.
// ---------------------------------------------------------------------------
__global__ __launch_bounds__(256, 4) void cls_mfma(
    const __hip_bfloat16* __restrict__ ftb,     // [8][M][32] bf16
    const __hip_bfloat16* __restrict__ Wcfrag,  // 64 groups x 512
    const float* __restrict__ bc,               // [104]
    float* __restrict__ out,                    // [M,104]
    int M)
{
    __shared__ __hip_bfloat16 lds[32 * 512];    // 32KB
    const int t    = threadIdx.x;
    const int lane = t & 63;
    const int w    = t >> 6;
    const int quad = lane >> 4;
    const int l16  = lane & 15;
    const int mw   = blockIdx.x * 64 + w * 16;

    int mrow = min(mw + l16, M - 1);
    bf16x8 ffrag[8];
#pragma unroll
    for (int k0 = 0; k0 < 8; ++k0)
        ffrag[k0] = *(const bf16x8*)(ftb + (size_t)k0 * M * 32 +
                                     (size_t)mrow * 32 + quad * 8);

    f32x4 acc[8];
#pragma unroll
    for (int nt = 0; nt < 8; ++nt) acc[nt] = (f32x4){0.f,0.f,0.f,0.f};

    for (int p = 0; p < 2; ++p) {
        if (p) __syncthreads();
#pragma unroll
        for (int it = 0; it < 8; ++it) {
            int idx = it * 256 + t;
            *(uint4*)(lds + (size_t)idx * 8) =
                *(const uint4*)(Wcfrag + (size_t)p * 16384 + (size_t)idx * 8);
        }
        __syncthreads();
#pragma unroll
        for (int kl = 0; kl < 4; ++kl) {
            int k0 = p * 4 + kl;
#pragma unroll
            for (int nt = 0; nt < 8; ++nt) {
                bf16x8 wf = *(const bf16x8*)(lds + (kl * 8 + nt) * 512 + lane * 8);
                acc[nt] = __builtin_amdgcn_mfma_f32_16x16x32_bf16(wf, ffrag[k0], acc[nt], 0, 0, 0);
            }
        }
    }

    int m = mw + l16;
    if (m < M) {
#pragma unroll
        for (int nt = 0; nt < 8; ++nt) {
            int c0 = nt * 16 + quad * 4;
            if (c0 <= 100) {
                float4 bia = *(const float4*)(bc + c0);
                float4 o;
                o.x = acc[nt][0] + bia.x;
                o.y = acc[nt][1] + bia.y;
                o.z = acc[nt][2] + bia.z;
                o.w = acc[nt][3] + bia.w;
                *(float4*)(out + (size_t)m * CC + c0) = o;
            }
        }
    }
}

// ---------------------------------------------------------------------------
extern "C" void kernel_launch(void* const* d_in, const int* in_sizes, int n_in,
                              void* d_out, int out_size, void* d_ws, size_t ws_size,
                              hipStream_t stream)
{
    const float* emb      = (const float*)d_in[0];
    const float* W        = (const float*)d_in[1];
    const float* bvec     = (const float*)d_in[2];
    const float* Wc       = (const float*)d_in[3];
    const float* bc       = (const float*)d_in[4];
    const int*   token_id = (const int*)d_in[5];
    const int*   src_idx  = (const int*)d_in[6];
    const int*   dst_idx  = (const int*)d_in[7];
    float*       out      = (float*)d_out;

    const int E     = in_sizes[6];
    const int Vemb  = in_sizes[0] / DD;
    const int n_dst = out_size / CC;
    (void)n_in; (void)ws_size;

    char* ws = (char*)d_ws;
    size_t off = 0;
    auto alloc = [&](size_t bytes) {
        void* p = ws + off;
        off = (off + bytes + 255) & ~(size_t)255;
        return p;
    };
    int* seg_start = (int*)alloc((size_t)n_dst * sizeof(int));
    int* seg_end   = (int*)alloc((size_t)n_dst * sizeof(int));
    int* last_tok  = (int*)alloc((size_t)n_dst * sizeof(int));
    int* edge_tok  = (int*)alloc((size_t)E * sizeof(int));
    __hip_bfloat16* embb   = (__hip_bfloat16*)alloc((size_t)Vemb * DD * 2);
    __hip_bfloat16* Webuf  = (__hip_bfloat16*)alloc((size_t)Vemb * DD * 2);
    __hip_bfloat16* ftb    = (__hip_bfloat16*)alloc((size_t)n_dst * DD * 2);
    __hip_bfloat16* Wfrag  = (__hip_bfloat16*)alloc((size_t)128 * 512 * 2);
    __hip_bfloat16* Wcfrag = (__hip_bfloat16*)alloc((size_t)64 * 512 * 2);

    const int PB = (E + 255) / 256;
    const int we_blocks  = (Vemb + 63) / 64;
    const int seg_blocks = NSL * ((n_dst + 63) / 64);
    const int cls_blocks = (n_dst + 63) / 64;

    prep_all<<<PB + 48, 256, 0, stream>>>(
        token_id, src_idx, dst_idx, seg_start, seg_end, edge_tok, last_tok, E, PB,
        W, Wc, Wfrag, Wcfrag);
    we_gemm<<<we_blocks, 256, 0, stream>>>(
        emb, Wfrag, Webuf, embb, Vemb);
    seg_rnn_kernel<<<seg_blocks, 256, 0, stream>>>(
        Webuf, embb, edge_tok, seg_start, seg_end, last_tok, bvec, ftb,
        n_dst, Vemb);
    cls_mfma<<<cls_blocks, 256, 0, stream>>>(
        ftb, Wcfrag, bc, out, n_dst);
}

// Round 6
// 185.846 us; speedup vs baseline: 1.0757x; 1.0757x over previous
//
#include <hip/hip_runtime.h>
#include <hip/hip_bf16.h>

#define DD 256
#define CC 104
#define NSL 8      // feature slices: 8 x 32 dims (64B) — one slice per XCD

typedef __bf16 bf16x8 __attribute__((ext_vector_type(8)));
typedef float  f32x4  __attribute__((ext_vector_type(4)));

__device__ inline float bu2f(unsigned short u) {
    return __uint_as_float(((unsigned)u) << 16);
}
__device__ inline unsigned short f2bu(float f) {
    __hip_bfloat16 h = __float2bfloat16(f);
    return *reinterpret_cast<unsigned short*>(&h);
}

// ---------------------------------------------------------------------------
// Kernel 1: prep — per-edge boundaries/tokens/last-token + W,Wc -> bf16 frags.
// Fragment layout (g = group, s = lane, j<8):
//   frag[g*512 + s*8 + j] = Wsrc[(nt*16 + (s&15))*256 + k0*32 + (s>>4)*8 + j]
//   W: g = k0*16 + nt (8 x 16);  Wc: g = k0*8 + nt (8 x 8, rows padded to 128)
// ---------------------------------------------------------------------------
__global__ void prep_all(
    const int* __restrict__ token_id,
    const int* __restrict__ src_idx,
    const int* __restrict__ dst_idx,
    int* __restrict__ seg_start,
    int* __restrict__ seg_end,
    int* __restrict__ edge_tok,
    int* __restrict__ last_tok,
    int E, int PB,
    const float* __restrict__ W,
    const float* __restrict__ Wc,
    __hip_bfloat16* __restrict__ Wfrag,
    __hip_bfloat16* __restrict__ Wcfrag)
{
    const int b = blockIdx.x;
    const int t = threadIdx.x;
    if (b < PB) {
        int e = b * 256 + t;
        if (e >= E) return;
        int d = dst_idx[e];
        int tok = token_id[src_idx[e]];
        edge_tok[e] = tok;
        if (e == 0 || dst_idx[e - 1] != d) seg_start[d] = e;
        if (e == E - 1 || dst_idx[e + 1] != d) { seg_end[d] = e + 1; last_tok[d] = tok; }
        return;
    }
    if (b < PB + 32) {                      // W fragment reorder
        int idx  = (b - PB) * 256 + t;      // 0..8191
        int lane = idx & 63, g = idx >> 6;  // g = k0*16 + nt
        int nt = g & 15, k0 = g >> 4;
        int r = nt * 16 + (lane & 15);
        int c = k0 * 32 + (lane >> 4) * 8;
        const float* src = W + (size_t)r * DD + c;
        float4 v0 = *(const float4*)(src);
        float4 v1 = *(const float4*)(src + 4);
        uint4 pk;
        pk.x = (unsigned)f2bu(v0.x) | ((unsigned)f2bu(v0.y) << 16);
        pk.y = (unsigned)f2bu(v0.z) | ((unsigned)f2bu(v0.w) << 16);
        pk.z = (unsigned)f2bu(v1.x) | ((unsigned)f2bu(v1.y) << 16);
        pk.w = (unsigned)f2bu(v1.z) | ((unsigned)f2bu(v1.w) << 16);
        *(uint4*)(Wfrag + (size_t)idx * 8) = pk;
        return;
    }
    {                                       // Wc fragment reorder (padded)
        int idx  = (b - PB - 32) * 256 + t; // 0..4095
        int lane = idx & 63, g = idx >> 6;  // g = k0*8 + nt
        int nt = g & 7, k0 = g >> 3;
        int r = nt * 16 + (lane & 15);      // 0..127
        int c = k0 * 32 + (lane >> 4) * 8;
        float4 v0 = make_float4(0.f,0.f,0.f,0.f);
        float4 v1 = make_float4(0.f,0.f,0.f,0.f);
        if (r < CC) {
            const float* src = Wc + (size_t)r * DD + c;
            v0 = *(const float4*)(src);
            v1 = *(const float4*)(src + 4);
        }
        uint4 pk;
        pk.x = (unsigned)f2bu(v0.x) | ((unsigned)f2bu(v0.y) << 16);
        pk.y = (unsigned)f2bu(v0.z) | ((unsigned)f2bu(v0.w) << 16);
        pk.z = (unsigned)f2bu(v1.x) | ((unsigned)f2bu(v1.y) << 16);
        pk.w = (unsigned)f2bu(v1.z) | ((unsigned)f2bu(v1.w) << 16);
        *(uint4*)(Wcfrag + (size_t)idx * 8) = pk;
    }
}

// ---------------------------------------------------------------------------
// Kernel 2: We = emb @ W^T for ALL tokens (dense streaming MFMA GEMM).
// Webuf and embb written SLICE-MAJOR: [slice=dim/32][V][32 dims] so each
// XCD's L2 can keep exactly its 3.2MB slice resident during the gather.
// ---------------------------------------------------------------------------
__global__ __launch_bounds__(256, 3) void we_gemm(
    const float* __restrict__ emb,             // [V,256] fp32
    const __hip_bfloat16* __restrict__ Wfrag,  // 128 groups x 512
    __hip_bfloat16* __restrict__ Webuf,        // [8][V][32] bf16 out
    __hip_bfloat16* __restrict__ embb,         // [8][V][32] bf16 out
    int V)
{
    __shared__ __hip_bfloat16 lds[32 * 512];   // 32KB
    const int t    = threadIdx.x;
    const int lane = t & 63;
    const int w    = t >> 6;
    const int quad = lane >> 4;
    const int l16  = lane & 15;
    const int mrow = blockIdx.x * 64 + w * 16 + l16;
    const int row  = min(mrow, V - 1);

    // stream emb row fp32 -> bf16 frags (+ embb slice-major side-write)
    bf16x8 bfrag[8];
#pragma unroll
    for (int k0 = 0; k0 < 8; ++k0) {
        const float* src = emb + (size_t)row * DD + k0 * 32 + quad * 8;
        float4 v0 = *(const float4*)(src);
        float4 v1 = *(const float4*)(src + 4);
        uint4 pk;
        pk.x = (unsigned)f2bu(v0.x) | ((unsigned)f2bu(v0.y) << 16);
        pk.y = (unsigned)f2bu(v0.z) | ((unsigned)f2bu(v0.w) << 16);
        pk.z = (unsigned)f2bu(v1.x) | ((unsigned)f2bu(v1.y) << 16);
        pk.w = (unsigned)f2bu(v1.z) | ((unsigned)f2bu(v1.w) << 16);
        bfrag[k0] = *(bf16x8*)&pk;
        if (mrow < V)   // slice k0, chunk quad*8 within slice
            *(uint4*)(embb + (size_t)k0 * V * 32 + (size_t)row * 32 + quad * 8) = pk;
    }

    f32x4 acc[16];
#pragma unroll
    for (int nt = 0; nt < 16; ++nt) acc[nt] = (f32x4){0.f,0.f,0.f,0.f};

    for (int p = 0; p < 4; ++p) {
        if (p) __syncthreads();
        // straight-copy groups [32p, 32p+32): 32KB
#pragma unroll
        for (int it = 0; it < 8; ++it) {
            int idx = it * 256 + t;
            *(uint4*)(lds + (size_t)idx * 8) =
                *(const uint4*)(Wfrag + (size_t)p * 16384 + (size_t)idx * 8);
        }
        __syncthreads();
#pragma unroll
        for (int kl = 0; kl < 2; ++kl) {
            int k0 = p * 2 + kl;
#pragma unroll
            for (int nt = 0; nt < 16; ++nt) {
                bf16x8 wf = *(const bf16x8*)(lds + (kl * 16 + nt) * 512 + lane * 8);
                acc[nt] = __builtin_amdgcn_mfma_f32_16x16x32_bf16(wf, bfrag[k0], acc[nt], 0, 0, 0);
            }
        }
    }

    if (mrow < V) {
#pragma unroll
        for (int nt = 0; nt < 16; ++nt) {
            int c0 = nt * 16 + quad * 4;    // starting dim of this 4-dim piece
            ushort4 o;
            o.x = f2bu(acc[nt][0]);
            o.y = f2bu(acc[nt][1]);
            o.z = f2bu(acc[nt][2]);
            o.w = f2bu(acc[nt][3]);
            *(ushort4*)(Webuf + (size_t)(c0 >> 5) * V * 32 +
                        (size_t)mrow * 32 + (c0 & 31)) = o;
        }
    }
}

// ---------------------------------------------------------------------------
// Kernel 3: segment sum + rnn epilogue, XCD-SLICED + BATCHED (R13).
// R12 proved slicing fixes the traffic wall (FETCH 156->63.6MB) but its
// 2-deep loop re-created the latency wall (2 gathers in flight, trip count
// = max n over 16 dsts ~25, dur 67us, VGPR=16). R13 combines both proven
// halves: keep the slice geometry, batch the child loop 8-deep:
//   per trip: 8 independent token loads -> 8 clamped gathers (all in
//   flight) -> sched_barrier(0) -> EXEC-masked accumulate. ~4 trips.
// Targets are L2-resident now, so each trip ~550cy instead of 8x600cy.
// launch_bounds(256,6): ~84 VGPR cap fits u[8](32)+tk+acc+lm (~60) without
// the R10 spill, at 24 waves/CU.
// ---------------------------------------------------------------------------
__global__ __launch_bounds__(256, 6) void seg_rnn_kernel(
    const __hip_bfloat16* __restrict__ Webuf,   // [8][V][32]
    const __hip_bfloat16* __restrict__ embb,    // [8][V][32]
    const int* __restrict__ edge_tok,
    const int* __restrict__ seg_start,
    const int* __restrict__ seg_end,
    const int* __restrict__ last_tok,
    const float* __restrict__ bvec,
    __hip_bfloat16* __restrict__ ftb,           // [8][n_dst][32]
    int n_dst, int V)
{
    const int bid  = blockIdx.x;
    const int sl   = bid & 7;                   // slice == XCD (round-robin)
    const int g    = bid >> 3;                  // dst-group of 64
    const int t    = threadIdx.x;
    const int wv   = t >> 6;
    const int lane = t & 63;
    const int grp  = lane >> 2;                 // dst within wave [0,16)
    const int c    = lane & 3;                  // 16B chunk within 64B slice

    int d = g * 64 + wv * 16 + grp;
    bool dok = d < n_dst;
    int dc = dok ? d : n_dst - 1;
    int s  = seg_start[dc];
    int e  = seg_end[dc];
    int lt = last_tok[dc];
    int n  = dok ? (e - 1 - s) : 0;             // children to sum (deg-1)
    int nm1 = n - 1;

    const __hip_bfloat16* wsl = Webuf + (size_t)sl * V * 32;
    const __hip_bfloat16* esl = embb  + (size_t)sl * V * 32;
    // last-message slice read (overlaps the loop below)
    uint4 lm = *(const uint4*)(esl + (size_t)lt * 32 + c * 8);

    float acc[8] = {0.f,0.f,0.f,0.f,0.f,0.f,0.f,0.f};

    for (int j0 = 0; __any(j0 < n); j0 += 8) {
        // 8 independent token loads (4 lanes/group load same addr: broadcast)
        int tk[8];
#pragma unroll
        for (int i = 0; i < 8; ++i) {
            int idx = j0 + i;
            idx = idx < nm1 ? idx : nm1;    // clamp high -> valid child
            idx = idx > 0 ? idx : 0;        // clamp low (n==0 -> nm1==-1)
            tk[i] = edge_tok[s + idx];
        }
        // 8 gathers, all in flight; clamped rows re-read a cached line
        uint4 u[8];
#pragma unroll
        for (int i = 0; i < 8; ++i)
            u[i] = *(const uint4*)(wsl + (size_t)tk[i] * 32 + c * 8);
        __builtin_amdgcn_sched_barrier(0);
#pragma unroll
        for (int i = 0; i < 8; ++i) {
            if (j0 + i < n) {               // per-group-uniform, EXEC-masked
                const unsigned* p = (const unsigned*)&u[i];
#pragma unroll
                for (int k = 0; k < 4; ++k) {
                    acc[2*k]   += __uint_as_float(p[k] << 16);
                    acc[2*k+1] += __uint_as_float(p[k] & 0xffff0000u);
                }
            }
        }
    }

    bool gate = n > 0;
    // epilogue: each lane owns 8 dims of its dst — no cross-lane reduce
    float4 b0 = *(const float4*)(bvec + sl * 32 + c * 8);
    float4 b1 = *(const float4*)(bvec + sl * 32 + c * 8 + 4);
    float bl[8] = {b0.x, b0.y, b0.z, b0.w, b1.x, b1.y, b1.z, b1.w};
    const unsigned* lmd = (const unsigned*)&lm;
    uint4 o;
    unsigned* od = (unsigned*)&o;
#pragma unroll
    for (int k = 0; k < 4; ++k) {
        float lo = __uint_as_float(lmd[k] << 16);
        float hi = __uint_as_float(lmd[k] & 0xffff0000u);
        float v0 = lo + (gate ? fmaxf(acc[2*k]   + bl[2*k],   0.f) : 0.f);
        float v1 = hi + (gate ? fmaxf(acc[2*k+1] + bl[2*k+1], 0.f) : 0.f);
        od[k] = (unsigned)f2bu(v0) | ((unsigned)f2bu(v1) << 16);
    }
    if (dok)    // wave stores 16 dsts x 64B = 1KB contiguous per slice
        *(uint4*)(ftb + (size_t)sl * n_dst * 32 + (size_t)d * 32 + c * 8) = o;
}

// ---------------------------------------------------------------------------
// Kernel 4: classifier GEMM. 64-row blocks, Wcfrag staged via straight
// 32KB copies (2 phases). ftb is slice-major [8][M][32]; k0 == slice.
// ---------------------------------------------------------------------------
__global__ __launch_bounds__(256, 4) void cls_mfma(
    const __hip_bfloat16* __restrict__ ftb,     // [8][M][32] bf16
    const __hip_bfloat16* __restrict__ Wcfrag,  // 64 groups x 512
    const float* __restrict__ bc,               // [104]
    float* __restrict__ out,                    // [M,104]
    int M)
{
    __shared__ __hip_bfloat16 lds[32 * 512];    // 32KB
    const int t    = threadIdx.x;
    const int lane = t & 63;
    const int w    = t >> 6;
    const int quad = lane >> 4;
    const int l16  = lane & 15;
    const int mw   = blockIdx.x * 64 + w * 16;

    int mrow = min(mw + l16, M - 1);
    bf16x8 ffrag[8];
#pragma unroll
    for (int k0 = 0; k0 < 8; ++k0)
        ffrag[k0] = *(const bf16x8*)(ftb + (size_t)k0 * M * 32 +
                                     (size_t)mrow * 32 + quad * 8);

    f32x4 acc[8];
#pragma unroll
    for (int nt = 0; nt < 8; ++nt) acc[nt] = (f32x4){0.f,0.f,0.f,0.f};

    for (int p = 0; p < 2; ++p) {
        if (p) __syncthreads();
#pragma unroll
        for (int it = 0; it < 8; ++it) {
            int idx = it * 256 + t;
            *(uint4*)(lds + (size_t)idx * 8) =
                *(const uint4*)(Wcfrag + (size_t)p * 16384 + (size_t)idx * 8);
        }
        __syncthreads();
#pragma unroll
        for (int kl = 0; kl < 4; ++kl) {
            int k0 = p * 4 + kl;
#pragma unroll
            for (int nt = 0; nt < 8; ++nt) {
                bf16x8 wf = *(const bf16x8*)(lds + (kl * 8 + nt) * 512 + lane * 8);
                acc[nt] = __builtin_amdgcn_mfma_f32_16x16x32_bf16(wf, ffrag[k0], acc[nt], 0, 0, 0);
            }
        }
    }

    int m = mw + l16;
    if (m < M) {
#pragma unroll
        for (int nt = 0; nt < 8; ++nt) {
            int c0 = nt * 16 + quad * 4;
            if (c0 <= 100) {
                float4 bia = *(const float4*)(bc + c0);
                float4 o;
                o.x = acc[nt][0] + bia.x;
                o.y = acc[nt][1] + bia.y;
                o.z = acc[nt][2] + bia.z;
                o.w = acc[nt][3] + bia.w;
                *(float4*)(out + (size_t)m * CC + c0) = o;
            }
        }
    }
}

// ---------------------------------------------------------------------------
extern "C" void kernel_launch(void* const* d_in, const int* in_sizes, int n_in,
                              void* d_out, int out_size, void* d_ws, size_t ws_size,
                              hipStream_t stream)
{
    const float* emb      = (const float*)d_in[0];
    const float* W        = (const float*)d_in[1];
    const float* bvec     = (const float*)d_in[2];
    const float* Wc       = (const float*)d_in[3];
    const float* bc       = (const float*)d_in[4];
    const int*   token_id = (const int*)d_in[5];
    const int*   src_idx  = (const int*)d_in[6];
    const int*   dst_idx  = (const int*)d_in[7];
    float*       out      = (float*)d_out;

    const int E     = in_sizes[6];
    const int Vemb  = in_sizes[0] / DD;
    const int n_dst = out_size / CC;
    (void)n_in; (void)ws_size;

    char* ws = (char*)d_ws;
    size_t off = 0;
    auto alloc = [&](size_t bytes) {
        void* p = ws + off;
        off = (off + bytes + 255) & ~(size_t)255;
        return p;
    };
    int* seg_start = (int*)alloc((size_t)n_dst * sizeof(int));
    int* seg_end   = (int*)alloc((size_t)n_dst * sizeof(int));
    int* last_tok  = (int*)alloc((size_t)n_dst * sizeof(int));
    int* edge_tok  = (int*)alloc((size_t)E * sizeof(int));
    __hip_bfloat16* embb   = (__hip_bfloat16*)alloc((size_t)Vemb * DD * 2);
    __hip_bfloat16* Webuf  = (__hip_bfloat16*)alloc((size_t)Vemb * DD * 2);
    __hip_bfloat16* ftb    = (__hip_bfloat16*)alloc((size_t)n_dst * DD * 2);
    __hip_bfloat16* Wfrag  = (__hip_bfloat16*)alloc((size_t)128 * 512 * 2);
    __hip_bfloat16* Wcfrag = (__hip_bfloat16*)alloc((size_t)64 * 512 * 2);

    const int PB = (E + 255) / 256;
    const int we_blocks  = (Vemb + 63) / 64;
    const int seg_blocks = NSL * ((n_dst + 63) / 64);
    const int cls_blocks = (n_dst + 63) / 64;

    prep_all<<<PB + 48, 256, 0, stream>>>(
        token_id, src_idx, dst_idx, seg_start, seg_end, edge_tok, last_tok, E, PB,
        W, Wc, Wfrag, Wcfrag);
    we_gemm<<<we_blocks, 256, 0, stream>>>(
        emb, Wfrag, Webuf, embb, Vemb);
    seg_rnn_kernel<<<seg_blocks, 256, 0, stream>>>(
        Webuf, embb, edge_tok, seg_start, seg_end, last_tok, bvec, ftb,
        n_dst, Vemb);
    cls_mfma<<<cls_blocks, 256, 0, stream>>>(
        ftb, Wcfrag, bc, out, n_dst);
}